// Round 11
// baseline (2006.335 us; speedup 1.0000x reference)
//
#include <hip/hip_runtime.h>
#include <stdint.h>

#define MROWS  200704
#define SCALE_ 0.17677669529663687f  // 32^-0.5

typedef __attribute__((ext_vector_type(8))) short bf16x8;
typedef __attribute__((ext_vector_type(4))) float f32x4;
union V8 { uint4 u; unsigned short s[8]; };

__device__ __forceinline__ float bf2f(unsigned short u) {
  union { unsigned int i; float f; } c; c.i = ((unsigned int)u) << 16; return c.f;
}
__device__ __forceinline__ unsigned short f2bf(float f) {
  union { float f; unsigned int i; } c; c.f = f;
  unsigned int lsb = (c.i >> 16) & 1;
  return (unsigned short)((c.i + 0x7fffu + lsb) >> 16);
}
// tanh-form GELU, exp-based; validated round 5/7
__device__ __forceinline__ float gelu_f(float x) {
  float x2 = x * x;
  float arg = x * fmaf(0.07135481f, x2, 1.59576912f);
  float e = __expf(arg);
  float r = __builtin_amdgcn_rcpf(1.0f + e);
  return fmaf(-x, r, x);
}

// ---------------- weight convert+transpose: W (K x N fp32) -> Wt (N x K bf16) ----------------
__global__ __launch_bounds__(256) void wt_k(const float* __restrict__ W,
    unsigned short* __restrict__ Wt, int K, int N)
{
  int idx = blockIdx.x * 256 + threadIdx.x;
  if (idx < K * N) {
    int k = idx / N, n = idx - k * N;
    Wt[(size_t)n * K + k] = f2bf(W[idx]);
  }
}

// ---------------- FUSED LN1 (windowed gather) + QKV GEMM ----------------
__global__ __launch_bounds__(256, 3) void qkvf_k(const float* __restrict__ X,
    const float* __restrict__ g, const float* __restrict__ b,
    const unsigned short* __restrict__ Wt,   // [576][192] bf16
    const float* __restrict__ bias,
    unsigned short* __restrict__ C, int shift)
{
  __shared__ unsigned short As[128][200];
  const int tid = threadIdx.x, lane = tid & 63, wv = tid >> 6;
  const int row0 = blockIdx.x * 128;
  #pragma unroll 2
  for (int r = 0; r < 32; ++r) {
    int row = wv * 32 + r, wr = row0 + row;
    int win = wr / 49, n = wr - win * 49;
    int bi = win >> 6, w64 = win & 63, wh = w64 >> 3, ww = w64 & 7;
    int ti = n / 7, tj = n - ti * 7;
    int gh = wh*7 + ti + shift; if (gh >= 56) gh -= 56;
    int gw = ww*7 + tj + shift; if (gw >= 56) gw -= 56;
    const float* xr = X + ((size_t)bi*3136 + gh*56 + gw) * 192;
    float v0 = xr[lane], v1 = xr[lane + 64], v2 = xr[lane + 128];
    float s  = v0 + v1 + v2;
    float s2 = v0*v0 + v1*v1 + v2*v2;
    #pragma unroll
    for (int m = 32; m >= 1; m >>= 1) { s += __shfl_xor(s, m); s2 += __shfl_xor(s2, m); }
    float mean = s * (1.0f/192.0f);
    float var  = s2 * (1.0f/192.0f) - mean*mean;
    float inv  = rsqrtf(var + 1e-5f);
    As[row][lane]     = f2bf((v0-mean)*inv*g[lane]      + b[lane]);
    As[row][lane+64]  = f2bf((v1-mean)*inv*g[lane+64]   + b[lane+64]);
    As[row][lane+128] = f2bf((v2-mean)*inv*g[lane+128]  + b[lane+128]);
  }
  __syncthreads();   // the ONLY barrier
  const int wm = wv >> 1, wn = wv & 1;
  const int fr = lane & 15, kq = (lane >> 4) * 8;
  const int lr4 = (lane >> 4) * 4;
  #pragma unroll 1
  for (int p = 0; p < 9; ++p) {
    bf16x8 bfr[6][2];
    #pragma unroll
    for (int ks = 0; ks < 6; ++ks)
      #pragma unroll
      for (int ni = 0; ni < 2; ++ni)
        bfr[ks][ni] = *reinterpret_cast<const bf16x8*>(
            &Wt[(size_t)(p*64 + wn*32 + ni*16 + fr) * 192 + ks*32 + kq]);
    f32x4 acc[4][2] = {};
    #pragma unroll
    for (int ks = 0; ks < 6; ++ks)
      #pragma unroll
      for (int mi = 0; mi < 4; ++mi) {
        bf16x8 afr = *reinterpret_cast<const bf16x8*>(&As[wm*64 + mi*16 + fr][ks*32 + kq]);
        #pragma unroll
        for (int ni = 0; ni < 2; ++ni)
          acc[mi][ni] = __builtin_amdgcn_mfma_f32_16x16x32_bf16(afr, bfr[ks][ni], acc[mi][ni], 0, 0, 0);
      }
    #pragma unroll
    for (int mi = 0; mi < 4; ++mi)
    #pragma unroll
    for (int ni = 0; ni < 2; ++ni)
    #pragma unroll
    for (int i = 0; i < 4; ++i) {
      int gr = row0 + wm*64 + mi*16 + lr4 + i;
      int gc = p*64 + wn*32 + ni*16 + fr;
      C[(size_t)gr * 576 + gc] = f2bf(acc[mi][ni][i] + bias[gc]);
    }
  }
}

// ---------------- proj GEMM + window-reverse scatter residual (r7 structure) ----------------
__global__ __launch_bounds__(256, 4) void proj_k(
    const unsigned short* __restrict__ A,
    const unsigned short* __restrict__ Wt,   // [192][192] bf16
    const float* __restrict__ bias,
    const float* __restrict__ Xres,
    float* __restrict__ Xdst,
    int shift)
{
  __shared__ unsigned short As[128][40];
  const int tid = threadIdx.x;
  const int lane = tid & 63, wv = tid >> 6;
  const int wm = wv >> 1, wn = wv & 1;
  const int row0 = blockIdx.x * 128;
  const int n0   = blockIdx.y * 64;
  const int fr = lane & 15, kq = (lane >> 4) * 8;
  bf16x8 bfr[6][2];
  #pragma unroll
  for (int ks = 0; ks < 6; ++ks)
    #pragma unroll
    for (int ni = 0; ni < 2; ++ni)
      bfr[ks][ni] = *reinterpret_cast<const bf16x8*>(
          &Wt[(size_t)(n0 + wn*32 + ni*16 + fr) * 192 + ks*32 + kq]);
  const int sr  = tid >> 1, ssg = (tid & 1) * 16;
  const unsigned short* arow = A + (size_t)(row0 + sr) * 192 + ssg;
  uint4 a0 = *reinterpret_cast<const uint4*>(arow);
  uint4 a1 = *reinterpret_cast<const uint4*>(arow + 8);
  f32x4 acc[4][2] = {};
  #pragma unroll
  for (int ks = 0; ks < 6; ++ks) {
    __syncthreads();
    *reinterpret_cast<uint4*>(&As[sr][ssg])     = a0;
    *reinterpret_cast<uint4*>(&As[sr][ssg + 8]) = a1;
    if (ks < 5) {
      a0 = *reinterpret_cast<const uint4*>(arow + (ks+1)*32);
      a1 = *reinterpret_cast<const uint4*>(arow + (ks+1)*32 + 8);
    }
    __syncthreads();
    #pragma unroll
    for (int mi = 0; mi < 4; ++mi) {
      bf16x8 afr = *reinterpret_cast<const bf16x8*>(&As[wm*64 + mi*16 + fr][kq]);
      #pragma unroll
      for (int ni = 0; ni < 2; ++ni)
        acc[mi][ni] = __builtin_amdgcn_mfma_f32_16x16x32_bf16(afr, bfr[ks][ni], acc[mi][ni], 0, 0, 0);
    }
  }
  const int lcol = lane & 15, lr4 = (lane >> 4) * 4;
  #pragma unroll
  for (int mi = 0; mi < 4; ++mi)
  #pragma unroll
  for (int ni = 0; ni < 2; ++ni)
  #pragma unroll
  for (int i = 0; i < 4; ++i) {
    int gr = row0 + wm*64 + mi*16 + lr4 + i;
    int gc = n0 + wn*32 + ni*16 + lcol;
    float v = acc[mi][ni][i] + bias[gc];
    int win = gr / 49, n = gr % 49;
    int bi = win >> 6, w64 = win & 63;
    int wh = w64 >> 3, ww = w64 & 7;
    int ti = n / 7, tj = n % 7;
    int gh = wh*7 + ti + shift; if (gh >= 56) gh -= 56;
    int gw = ww*7 + tj + shift; if (gw >= 56) gw -= 56;
    size_t idx = ((size_t)bi * 3136 + gh * 56 + gw) * 192 + gc;
    Xdst[idx] = Xres[idx] + v;
  }
}

// ---------------- Fused LN2 + FC1 + GELU + FC2 + residual ----------------
// r7 structure; ONE change: rolling 2-buffer weight prefetch (1-deep in FC1,
// 2-deep in FC2 with first loads issued before the GELU barriers).
__global__ __launch_bounds__(512, 3) void mlp_k(
    const float* __restrict__ X,
    const float* __restrict__ g, const float* __restrict__ b,
    const unsigned short* __restrict__ W1t, // [768][192] bf16
    const float* __restrict__ b1,
    const unsigned short* __restrict__ W2t, // [192][768] bf16
    const float* __restrict__ b2,
    float* __restrict__ Y)
{
  __shared__ unsigned short As[64][200];
  __shared__ unsigned short Hs[64][396];
  const int row0 = blockIdx.x * 64;
  const int tid = threadIdx.x, lane = tid & 63, wv = tid >> 6;
  #pragma unroll
  for (int r = 0; r < 8; ++r) {
    int row = wv * 8 + r;
    const float* xr = X + (size_t)(row0 + row) * 192;
    float v0 = xr[lane], v1 = xr[lane + 64], v2 = xr[lane + 128];
    float s  = v0 + v1 + v2;
    float s2 = v0*v0 + v1*v1 + v2*v2;
    #pragma unroll
    for (int m = 32; m >= 1; m >>= 1) { s += __shfl_xor(s, m); s2 += __shfl_xor(s2, m); }
    float mean = s * (1.0f/192.0f);
    float var  = s2 * (1.0f/192.0f) - mean*mean;
    float inv  = rsqrtf(var + 1e-5f);
    As[row][lane]       = f2bf((v0-mean)*inv*g[lane]      + b[lane]);
    As[row][lane+64]    = f2bf((v1-mean)*inv*g[lane+64]   + b[lane+64]);
    As[row][lane+128]   = f2bf((v2-mean)*inv*g[lane+128]  + b[lane+128]);
  }
  __syncthreads();
  const int fr = lane & 15, kq = (lane >> 4) * 8;
  const int lcol = lane & 15, lr4 = (lane >> 4) * 4;
  const int wm2 = wv >> 2, wn2 = wv & 3;    // FC2 wave grid: 2 x 4
  f32x4 acc2[2][3] = {};

#define LD1(dst, ks) { dst[0] = *reinterpret_cast<const bf16x8*>(w1p0 + (ks)*32); \
                       dst[1] = *reinterpret_cast<const bf16x8*>(w1p1 + (ks)*32); \
                       dst[2] = *reinterpret_cast<const bf16x8*>(w1p2 + (ks)*32); }
#define FMA1(bb, ks) { _Pragma("unroll") \
  for (int mi = 0; mi < 4; ++mi) { \
    bf16x8 afr = *reinterpret_cast<const bf16x8*>(&As[mi*16 + fr][(ks)*32 + kq]); \
    acc1[mi][0] = __builtin_amdgcn_mfma_f32_16x16x32_bf16(afr, bb[0], acc1[mi][0], 0, 0, 0); \
    acc1[mi][1] = __builtin_amdgcn_mfma_f32_16x16x32_bf16(afr, bb[1], acc1[mi][1], 0, 0, 0); \
    acc1[mi][2] = __builtin_amdgcn_mfma_f32_16x16x32_bf16(afr, bb[2], acc1[mi][2], 0, 0, 0); } }
#define LD2(dst, ks) { dst[0] = *reinterpret_cast<const bf16x8*>(w2p0 + (ks)*32); \
                       dst[1] = *reinterpret_cast<const bf16x8*>(w2p1 + (ks)*32); \
                       dst[2] = *reinterpret_cast<const bf16x8*>(w2p2 + (ks)*32); }
#define FMA2(bb, ks) { _Pragma("unroll") \
  for (int mi = 0; mi < 2; ++mi) { \
    bf16x8 afr = *reinterpret_cast<const bf16x8*>(&Hs[wm2*32 + mi*16 + fr][(ks)*32 + kq]); \
    acc2[mi][0] = __builtin_amdgcn_mfma_f32_16x16x32_bf16(afr, bb[0], acc2[mi][0], 0, 0, 0); \
    acc2[mi][1] = __builtin_amdgcn_mfma_f32_16x16x32_bf16(afr, bb[1], acc2[mi][1], 0, 0, 0); \
    acc2[mi][2] = __builtin_amdgcn_mfma_f32_16x16x32_bf16(afr, bb[2], acc2[mi][2], 0, 0, 0); } }

  for (int hh = 0; hh < 2; ++hh) {
    const int c0 = hh * 384 + wv * 48;
    const unsigned short* w1p0 = &W1t[(size_t)(c0 +  0 + fr) * 192 + kq];
    const unsigned short* w1p1 = &W1t[(size_t)(c0 + 16 + fr) * 192 + kq];
    const unsigned short* w1p2 = &W1t[(size_t)(c0 + 32 + fr) * 192 + kq];
    const unsigned short* w2p0 = &W2t[(size_t)(wn2*48 +  0 + fr) * 768 + hh*384 + kq];
    const unsigned short* w2p1 = &W2t[(size_t)(wn2*48 + 16 + fr) * 768 + hh*384 + kq];
    const unsigned short* w2p2 = &W2t[(size_t)(wn2*48 + 32 + fr) * 768 + hh*384 + kq];
    // ---- FC1 with rolling 1-deep prefetch
    f32x4 acc1[4][3] = {};
    bf16x8 ba[3], bb[3];
    LD1(ba, 0);
    LD1(bb, 1); FMA1(ba, 0);
    LD1(ba, 2); FMA1(bb, 1);
    LD1(bb, 3); FMA1(ba, 2);
    LD1(ba, 4); FMA1(bb, 3);
    LD1(bb, 5); FMA1(ba, 4);
    // issue FC2 steps 0,1 before barriers (overlap barrier + GELU)
    bf16x8 ca[3], cb[3];
    LD2(ca, 0);
    LD2(cb, 1);
    FMA1(bb, 5);
    __syncthreads();   // previous half's FC2 finished reading Hs
    #pragma unroll
    for (int mi = 0; mi < 4; ++mi)
    #pragma unroll
    for (int ni = 0; ni < 3; ++ni)
    #pragma unroll
    for (int i = 0; i < 4; ++i) {
      int rr = mi*16 + lr4 + i;
      int cc = wv*48 + ni*16 + lcol;
      float v = acc1[mi][ni][i] + b1[hh*384 + cc];
      Hs[rr][cc] = f2bf(gelu_f(v));
    }
    __syncthreads();   // Hs ready
    // ---- FC2 with rolling 2-deep prefetch
    FMA2(ca, 0);  LD2(ca, 2);
    FMA2(cb, 1);  LD2(cb, 3);
    FMA2(ca, 2);  LD2(ca, 4);
    FMA2(cb, 3);  LD2(cb, 5);
    FMA2(ca, 4);  LD2(ca, 6);
    FMA2(cb, 5);  LD2(cb, 7);
    FMA2(ca, 6);  LD2(ca, 8);
    FMA2(cb, 7);  LD2(cb, 9);
    FMA2(ca, 8);  LD2(ca, 10);
    FMA2(cb, 9);  LD2(cb, 11);
    FMA2(ca, 10);
    FMA2(cb, 11);
  }
#undef LD1
#undef FMA1
#undef LD2
#undef FMA2
  #pragma unroll
  for (int mi = 0; mi < 2; ++mi)
  #pragma unroll
  for (int ni = 0; ni < 3; ++ni)
  #pragma unroll
  for (int i = 0; i < 4; ++i) {
    int grow = row0 + wm2*32 + mi*16 + lr4 + i;
    int gc = wn2*48 + ni*16 + lcol;
    float v = acc2[mi][ni][i] + b2[gc];
    size_t idx = (size_t)grow * 192 + gc;
    Y[idx] = X[idx] + v;
  }
}

// ---------------- Windowed attention: one wave per (window, head) ----------------
template<bool SHIFTED>
__global__ __launch_bounds__(64) void attn_k(
    const unsigned short* __restrict__ qkv,
    const float* __restrict__ rpb,
    unsigned short* __restrict__ out)
{
  __shared__ float kv[2][49][32];
  int blk = blockIdx.x;
  int win = blk / 6, h = blk - win * 6;
  int lane = threadIdx.x;
  const unsigned short* base = qkv + (size_t)win * 49 * 576;
  for (int idx = lane; idx < 196; idx += 64) {
    int n = idx >> 2, sg = (idx & 3) * 8;
    V8 kk, vv;
    kk.u = *reinterpret_cast<const uint4*>(base + n*576 + 192 + h*32 + sg);
    vv.u = *reinterpret_cast<const uint4*>(base + n*576 + 384 + h*32 + sg);
    #pragma unroll
    for (int j = 0; j < 8; ++j) { kv[0][n][sg+j] = bf2f(kk.s[j]); kv[1][n][sg+j] = bf2f(vv.s[j]); }
  }
  __syncthreads();
  if (lane < 49) {
    float q[32];
    const unsigned short* qr = base + (size_t)lane * 576 + h * 32;
    #pragma unroll
    for (int sg = 0; sg < 4; ++sg) {
      V8 qq; qq.u = *reinterpret_cast<const uint4*>(qr + sg*8);
      #pragma unroll
      for (int j = 0; j < 8; ++j) q[sg*8+j] = bf2f(qq.s[j]) * SCALE_;
    }
    int ti = lane / 7, tj = lane - ti * 7;
    int wi = win & 63, wh = wi >> 3, ww = wi & 7;
    int rid = 0;
    if (SHIFTED) {
      int hh = wh*7 + ti, wg = ww*7 + tj;
      rid = (hh < 49 ? 0 : (hh < 53 ? 1 : 2)) * 3 + (wg < 49 ? 0 : (wg < 53 ? 1 : 2));
    }
    float s[49];
    float mx = -1e30f;
    #pragma unroll
    for (int m = 0; m < 49; ++m) {
      float a = 0.f;
      #pragma unroll
      for (int d4 = 0; d4 < 8; ++d4) {
        float4 kf = *reinterpret_cast<const float4*>(&kv[0][m][d4*4]);
        a += q[d4*4+0]*kf.x + q[d4*4+1]*kf.y + q[d4*4+2]*kf.z + q[d4*4+3]*kf.w;
      }
      int mi = m / 7, mj = m - mi * 7;
      a += rpb[((ti - mi + 6) * 13 + (tj - mj + 6)) * 6 + h];
      if (SHIFTED) {
        int hh = wh*7 + mi, wg = ww*7 + mj;
        int rid2 = (hh < 49 ? 0 : (hh < 53 ? 1 : 2)) * 3 + (wg < 49 ? 0 : (wg < 53 ? 1 : 2));
        if (rid2 != rid) a -= 100.f;
      }
      s[m] = a;
      mx = fmaxf(mx, a);
    }
    float sum = 0.f;
    #pragma unroll
    for (int m = 0; m < 49; ++m) { float e = __expf(s[m] - mx); s[m] = e; sum += e; }
    float rs = 1.f / sum;
    float o[32];
    #pragma unroll
    for (int d = 0; d < 32; ++d) o[d] = 0.f;
    #pragma unroll
    for (int m = 0; m < 49; ++m) {
      float p = s[m] * rs;
      #pragma unroll
      for (int d4 = 0; d4 < 8; ++d4) {
        float4 vf = *reinterpret_cast<const float4*>(&kv[1][m][d4*4]);
        o[d4*4+0] += p*vf.x; o[d4*4+1] += p*vf.y; o[d4*4+2] += p*vf.z; o[d4*4+3] += p*vf.w;
      }
    }
    unsigned short* orow = out + ((size_t)win * 49 + lane) * 192 + h * 32;
    #pragma unroll
    for (int sg = 0; sg < 4; ++sg) {
      V8 pk;
      #pragma unroll
      for (int j = 0; j < 8; ++j) pk.s[j] = f2bf(o[sg*8+j]);
      *reinterpret_cast<uint4*>(orow + sg*8) = pk.u;
    }
  }
}

// ---------------- launch ----------------
extern "C" void kernel_launch(void* const* d_in, const int* in_sizes, int n_in,
                              void* d_out, int out_size, void* d_ws, size_t ws_size,
                              hipStream_t stream) {
  const float* x    = (const float*)d_in[0];
  const float* n1g  = (const float*)d_in[1];
  const float* n1b  = (const float*)d_in[2];
  const float* qkvw = (const float*)d_in[3];
  const float* qkvb = (const float*)d_in[4];
  const float* rpb  = (const float*)d_in[5];
  const float* pw   = (const float*)d_in[6];
  const float* pb   = (const float*)d_in[7];
  const float* n2g  = (const float*)d_in[8];
  const float* n2b  = (const float*)d_in[9];
  const float* f1w  = (const float*)d_in[10];
  const float* f1b  = (const float*)d_in[11];
  const float* f2w  = (const float*)d_in[12];
  const float* f2b  = (const float*)d_in[13];
  float* out = (float*)d_out;

  const size_t XBYTES = (size_t)MROWS * 192 * 4;
  const size_t ABYTES = (size_t)MROWS * 192 * 2;
  const size_t QBYTES = (size_t)MROWS * 576 * 2;
  char* ws = (char*)d_ws;
  float* x1 = (float*)ws;
  unsigned short* Abuf = (unsigned short*)(ws + XBYTES);
  unsigned short* Bbuf = (unsigned short*)(ws + XBYTES + ABYTES);
  unsigned short* WT   = (unsigned short*)(ws + XBYTES + ABYTES + QBYTES);
  const size_t WQ = 110592, WP = 36864, W1 = 147456, W2 = 147456;
  const size_t WD = WQ + WP + W1 + W2;

  for (int d = 0; d < 2; ++d) {
    unsigned short* wt = WT + d * WD;
    wt_k<<<(int)((WQ + 255)/256), 256, 0, stream>>>(qkvw + (size_t)d*WQ, wt,                 192, 576);
    wt_k<<<(int)((WP + 255)/256), 256, 0, stream>>>(pw   + (size_t)d*WP, wt + WQ,            192, 192);
    wt_k<<<(int)((W1 + 255)/256), 256, 0, stream>>>(f1w  + (size_t)d*W1, wt + WQ + WP,       192, 768);
    wt_k<<<(int)((W2 + 255)/256), 256, 0, stream>>>(f2w  + (size_t)d*W2, wt + WQ + WP + W1,  768, 192);
  }

  const dim3 G_P(MROWS/128, 3);

  for (int i = 0; i < 2; ++i) {
    int shift = i ? 3 : 0;
    const float* xin = i ? (const float*)x1 : x;
    float* xfin = i ? out : x1;
    const unsigned short* wt = WT + i * WD;
    // 1. fused LN1 + window gather + QKV gemm -> Bbuf
    qkvf_k<<<MROWS/128, 256, 0, stream>>>(xin, n1g + i*192, n1b + i*192, wt,
                                          qkvb + i*576, Bbuf, shift);
    // 2. attention -> Abuf
    if (shift) attn_k<true ><<<4096*6, 64, 0, stream>>>(Bbuf, rpb + i*169*6, Abuf);
    else       attn_k<false><<<4096*6, 64, 0, stream>>>(Bbuf, rpb + i*169*6, Abuf);
    // 3. proj gemm + window-reverse scatter residual -> x1
    proj_k<<<G_P, 256, 0, stream>>>(Abuf, wt + WQ, pb + i*192, xin, x1, shift);
    // 4. fused LN2 + FC1 + GELU + FC2 + residual
    mlp_k<<<MROWS/64, 512, 0, stream>>>(x1, n2g + i*192, n2b + i*192,
                                        wt + WQ + WP, f1b + i*768,
                                        wt + WQ + WP + W1, f2b + i*192, xfin);
  }
}

// Round 12
// 1995.691 us; speedup vs baseline: 1.0053x; 1.0053x over previous
//
#include <hip/hip_runtime.h>
#include <stdint.h>

#define MROWS  200704
#define SCALE_ 0.17677669529663687f  // 32^-0.5
#define WQ 110592
#define WP 36864
#define W1 147456
#define W2 147456
#define WD (WQ + WP + W1 + W2)

typedef __attribute__((ext_vector_type(8))) short bf16x8;
typedef __attribute__((ext_vector_type(4))) float f32x4;
union V8 { uint4 u; unsigned short s[8]; };

__device__ __forceinline__ float bf2f(unsigned short u) {
  union { unsigned int i; float f; } c; c.i = ((unsigned int)u) << 16; return c.f;
}
__device__ __forceinline__ unsigned short f2bf(float f) {
  union { float f; unsigned int i; } c; c.f = f;
  unsigned int lsb = (c.i >> 16) & 1;
  return (unsigned short)((c.i + 0x7fffu + lsb) >> 16);
}
// tanh-form GELU, exp-based; validated round 5/7
__device__ __forceinline__ float gelu_f(float x) {
  float x2 = x * x;
  float arg = x * fmaf(0.07135481f, x2, 1.59576912f);
  float e = __expf(arg);
  float r = __builtin_amdgcn_rcpf(1.0f + e);
  return fmaf(-x, r, x);
}

// ---------------- combined weight convert+transpose (all 4 weights, both depths) ----------------
__global__ __launch_bounds__(256) void wtall_k(const float* __restrict__ qkvw,
    const float* __restrict__ pw, const float* __restrict__ f1w,
    const float* __restrict__ f2w, unsigned short* __restrict__ WT)
{
  int d = blockIdx.y;
  int j = blockIdx.x * 256 + threadIdx.x;
  if (j >= WD) return;
  unsigned short* wt = WT + (size_t)d * WD;
  if (j < WQ) {
    const float* W = qkvw + (size_t)d * WQ;
    int k = j / 576, n = j - k * 576;
    wt[n * 192 + k] = f2bf(W[j]);
  } else if (j < WQ + WP) {
    int j2 = j - WQ;
    const float* W = pw + (size_t)d * WP;
    int k = j2 / 192, n = j2 - k * 192;
    (wt + WQ)[n * 192 + k] = f2bf(W[j2]);
  } else if (j < WQ + WP + W1) {
    int j2 = j - WQ - WP;
    const float* W = f1w + (size_t)d * W1;
    int k = j2 / 768, n = j2 - k * 768;
    (wt + WQ + WP)[n * 192 + k] = f2bf(W[j2]);
  } else {
    int j2 = j - WQ - WP - W1;
    const float* W = f2w + (size_t)d * W2;
    int k = j2 / 192, n = j2 - k * 192;
    (wt + WQ + WP + W1)[(size_t)n * 768 + k] = f2bf(W[j2]);
  }
}

// ---------------- FUSED LN1 (windowed gather) + QKV GEMM ----------------
// Output layout: Bbuf[win][qkv][head][tok][32]  (head-slice contiguous for attn)
__global__ __launch_bounds__(256, 3) void qkvf_k(const float* __restrict__ X,
    const float* __restrict__ g, const float* __restrict__ b,
    const unsigned short* __restrict__ Wt,   // [576][192] bf16
    const float* __restrict__ bias,
    unsigned short* __restrict__ C, int shift)
{
  __shared__ unsigned short As[128][200];
  const int tid = threadIdx.x, lane = tid & 63, wv = tid >> 6;
  const int row0 = blockIdx.x * 128;
  #pragma unroll 2
  for (int r = 0; r < 32; ++r) {
    int row = wv * 32 + r, wr = row0 + row;
    int win = wr / 49, n = wr - win * 49;
    int bi = win >> 6, w64 = win & 63, wh = w64 >> 3, ww = w64 & 7;
    int ti = n / 7, tj = n - ti * 7;
    int gh = wh*7 + ti + shift; if (gh >= 56) gh -= 56;
    int gw = ww*7 + tj + shift; if (gw >= 56) gw -= 56;
    const float* xr = X + ((size_t)bi*3136 + gh*56 + gw) * 192;
    float v0 = xr[lane], v1 = xr[lane + 64], v2 = xr[lane + 128];
    float s  = v0 + v1 + v2;
    float s2 = v0*v0 + v1*v1 + v2*v2;
    #pragma unroll
    for (int m = 32; m >= 1; m >>= 1) { s += __shfl_xor(s, m); s2 += __shfl_xor(s2, m); }
    float mean = s * (1.0f/192.0f);
    float var  = s2 * (1.0f/192.0f) - mean*mean;
    float inv  = rsqrtf(var + 1e-5f);
    As[row][lane]     = f2bf((v0-mean)*inv*g[lane]      + b[lane]);
    As[row][lane+64]  = f2bf((v1-mean)*inv*g[lane+64]   + b[lane+64]);
    As[row][lane+128] = f2bf((v2-mean)*inv*g[lane+128]  + b[lane+128]);
  }
  __syncthreads();   // the ONLY barrier
  const int wm = wv >> 1, wn = wv & 1;
  const int fr = lane & 15, kq = (lane >> 4) * 8;
  const int lr4 = (lane >> 4) * 4;
  #pragma unroll 1
  for (int p = 0; p < 9; ++p) {
    bf16x8 bfr[6][2];
    #pragma unroll
    for (int ks = 0; ks < 6; ++ks)
      #pragma unroll
      for (int ni = 0; ni < 2; ++ni)
        bfr[ks][ni] = *reinterpret_cast<const bf16x8*>(
            &Wt[(size_t)(p*64 + wn*32 + ni*16 + fr) * 192 + ks*32 + kq]);
    f32x4 acc[4][2] = {};
    #pragma unroll
    for (int ks = 0; ks < 6; ++ks)
      #pragma unroll
      for (int mi = 0; mi < 4; ++mi) {
        bf16x8 afr = *reinterpret_cast<const bf16x8*>(&As[wm*64 + mi*16 + fr][ks*32 + kq]);
        #pragma unroll
        for (int ni = 0; ni < 2; ++ni)
          acc[mi][ni] = __builtin_amdgcn_mfma_f32_16x16x32_bf16(afr, bfr[ks][ni], acc[mi][ni], 0, 0, 0);
      }
    #pragma unroll
    for (int mi = 0; mi < 4; ++mi)
    #pragma unroll
    for (int ni = 0; ni < 2; ++ni)
    #pragma unroll
    for (int i = 0; i < 4; ++i) {
      int gr = row0 + wm*64 + mi*16 + lr4 + i;
      int gc = p*64 + wn*32 + ni*16 + fr;
      int win = gr / 49, tok = gr - win * 49;
      int qkvi = gc / 192, rem = gc - qkvi * 192;
      int head = rem >> 5, dd = rem & 31;
      size_t off = ((size_t)(win*3 + qkvi)*6 + head) * 1568 + tok*32 + dd;
      C[off] = f2bf(acc[mi][ni][i] + bias[gc]);
    }
  }
}

// ---------------- proj GEMM + window-reverse scatter residual (r7 structure) ----------------
__global__ __launch_bounds__(256, 4) void proj_k(
    const unsigned short* __restrict__ A,
    const unsigned short* __restrict__ Wt,   // [192][192] bf16
    const float* __restrict__ bias,
    const float* __restrict__ Xres,
    float* __restrict__ Xdst,
    int shift)
{
  __shared__ unsigned short As[128][40];
  const int tid = threadIdx.x;
  const int lane = tid & 63, wv = tid >> 6;
  const int wm = wv >> 1, wn = wv & 1;
  const int row0 = blockIdx.x * 128;
  const int n0   = blockIdx.y * 64;
  const int fr = lane & 15, kq = (lane >> 4) * 8;
  bf16x8 bfr[6][2];
  #pragma unroll
  for (int ks = 0; ks < 6; ++ks)
    #pragma unroll
    for (int ni = 0; ni < 2; ++ni)
      bfr[ks][ni] = *reinterpret_cast<const bf16x8*>(
          &Wt[(size_t)(n0 + wn*32 + ni*16 + fr) * 192 + ks*32 + kq]);
  const int sr  = tid >> 1, ssg = (tid & 1) * 16;
  const unsigned short* arow = A + (size_t)(row0 + sr) * 192 + ssg;
  uint4 a0 = *reinterpret_cast<const uint4*>(arow);
  uint4 a1 = *reinterpret_cast<const uint4*>(arow + 8);
  f32x4 acc[4][2] = {};
  #pragma unroll
  for (int ks = 0; ks < 6; ++ks) {
    __syncthreads();
    *reinterpret_cast<uint4*>(&As[sr][ssg])     = a0;
    *reinterpret_cast<uint4*>(&As[sr][ssg + 8]) = a1;
    if (ks < 5) {
      a0 = *reinterpret_cast<const uint4*>(arow + (ks+1)*32);
      a1 = *reinterpret_cast<const uint4*>(arow + (ks+1)*32 + 8);
    }
    __syncthreads();
    #pragma unroll
    for (int mi = 0; mi < 4; ++mi) {
      bf16x8 afr = *reinterpret_cast<const bf16x8*>(&As[wm*64 + mi*16 + fr][kq]);
      #pragma unroll
      for (int ni = 0; ni < 2; ++ni)
        acc[mi][ni] = __builtin_amdgcn_mfma_f32_16x16x32_bf16(afr, bfr[ks][ni], acc[mi][ni], 0, 0, 0);
    }
  }
  const int lcol = lane & 15, lr4 = (lane >> 4) * 4;
  #pragma unroll
  for (int mi = 0; mi < 4; ++mi)
  #pragma unroll
  for (int ni = 0; ni < 2; ++ni)
  #pragma unroll
  for (int i = 0; i < 4; ++i) {
    int gr = row0 + wm*64 + mi*16 + lr4 + i;
    int gc = n0 + wn*32 + ni*16 + lcol;
    float v = acc[mi][ni][i] + bias[gc];
    int win = gr / 49, n = gr % 49;
    int bi = win >> 6, w64 = win & 63;
    int wh = w64 >> 3, ww = w64 & 7;
    int ti = n / 7, tj = n % 7;
    int gh = wh*7 + ti + shift; if (gh >= 56) gh -= 56;
    int gw = ww*7 + tj + shift; if (gw >= 56) gw -= 56;
    size_t idx = ((size_t)bi * 3136 + gh * 56 + gw) * 192 + gc;
    Xdst[idx] = Xres[idx] + v;
  }
}

// ---------------- Fused LN2 + FC1 + GELU + FC2 + residual (r7 verbatim) ----------------
__global__ __launch_bounds__(512, 4) void mlp_k(
    const float* __restrict__ X,
    const float* __restrict__ g, const float* __restrict__ b,
    const unsigned short* __restrict__ W1t, // [768][192] bf16
    const float* __restrict__ b1,
    const unsigned short* __restrict__ W2t, // [192][768] bf16
    const float* __restrict__ b2,
    float* __restrict__ Y)
{
  __shared__ unsigned short As[64][200];
  __shared__ unsigned short Hs[64][396];
  const int row0 = blockIdx.x * 64;
  const int tid = threadIdx.x, lane = tid & 63, wv = tid >> 6;
  #pragma unroll
  for (int r = 0; r < 8; ++r) {
    int row = wv * 8 + r;
    const float* xr = X + (size_t)(row0 + row) * 192;
    float v0 = xr[lane], v1 = xr[lane + 64], v2 = xr[lane + 128];
    float s  = v0 + v1 + v2;
    float s2 = v0*v0 + v1*v1 + v2*v2;
    #pragma unroll
    for (int m = 32; m >= 1; m >>= 1) { s += __shfl_xor(s, m); s2 += __shfl_xor(s2, m); }
    float mean = s * (1.0f/192.0f);
    float var  = s2 * (1.0f/192.0f) - mean*mean;
    float inv  = rsqrtf(var + 1e-5f);
    As[row][lane]       = f2bf((v0-mean)*inv*g[lane]      + b[lane]);
    As[row][lane+64]    = f2bf((v1-mean)*inv*g[lane+64]   + b[lane+64]);
    As[row][lane+128]   = f2bf((v2-mean)*inv*g[lane+128]  + b[lane+128]);
  }
  __syncthreads();
  const int fr = lane & 15, kq = (lane >> 4) * 8;
  const int lcol = lane & 15, lr4 = (lane >> 4) * 4;
  const int wm2 = wv >> 2, wn2 = wv & 3;    // FC2 wave grid: 2 x 4
  f32x4 acc2[2][3] = {};
  for (int hh = 0; hh < 2; ++hh) {
    f32x4 acc1[4][3] = {};
    const int c0 = hh * 384 + wv * 48;
    #pragma unroll
    for (int k0 = 0; k0 < 192; k0 += 32) {
      bf16x8 bfr[3];
      #pragma unroll
      for (int ni = 0; ni < 3; ++ni)
        bfr[ni] = *reinterpret_cast<const bf16x8*>(&W1t[(size_t)(c0 + ni*16 + fr) * 192 + k0 + kq]);
      #pragma unroll
      for (int mi = 0; mi < 4; ++mi) {
        bf16x8 afr = *reinterpret_cast<const bf16x8*>(&As[mi*16 + fr][k0 + kq]);
        #pragma unroll
        for (int ni = 0; ni < 3; ++ni)
          acc1[mi][ni] = __builtin_amdgcn_mfma_f32_16x16x32_bf16(afr, bfr[ni], acc1[mi][ni], 0, 0, 0);
      }
    }
    __syncthreads();   // previous half's FC2 finished reading Hs
    #pragma unroll
    for (int mi = 0; mi < 4; ++mi)
    #pragma unroll
    for (int ni = 0; ni < 3; ++ni)
    #pragma unroll
    for (int i = 0; i < 4; ++i) {
      int rr = mi*16 + lr4 + i;
      int cc = wv*48 + ni*16 + lcol;
      float v = acc1[mi][ni][i] + b1[hh*384 + cc];
      Hs[rr][cc] = f2bf(gelu_f(v));
    }
    __syncthreads();   // Hs ready
    #pragma unroll
    for (int k0 = 0; k0 < 384; k0 += 32) {
      bf16x8 bfr[3];
      #pragma unroll
      for (int ni = 0; ni < 3; ++ni)
        bfr[ni] = *reinterpret_cast<const bf16x8*>(
            &W2t[(size_t)(wn2*48 + ni*16 + fr) * 768 + hh*384 + k0 + kq]);
      #pragma unroll
      for (int mi = 0; mi < 2; ++mi) {
        bf16x8 afr = *reinterpret_cast<const bf16x8*>(&Hs[wm2*32 + mi*16 + fr][k0 + kq]);
        #pragma unroll
        for (int ni = 0; ni < 3; ++ni)
          acc2[mi][ni] = __builtin_amdgcn_mfma_f32_16x16x32_bf16(afr, bfr[ni], acc2[mi][ni], 0, 0, 0);
      }
    }
  }
  #pragma unroll
  for (int mi = 0; mi < 2; ++mi)
  #pragma unroll
  for (int ni = 0; ni < 3; ++ni)
  #pragma unroll
  for (int i = 0; i < 4; ++i) {
    int grow = row0 + wm2*32 + mi*16 + lr4 + i;
    int gc = wn2*48 + ni*16 + lcol;
    float v = acc2[mi][ni][i] + b2[gc];
    size_t idx = (size_t)grow * 192 + gc;
    Y[idx] = X[idx] + v;
  }
}

// ---------------- Windowed attention: one wave per (window, head) ----------------
// qkv layout: [win][qkv][head][tok][32] -> K/V slices fully contiguous (3136 B)
template<bool SHIFTED>
__global__ __launch_bounds__(64) void attn_k(
    const unsigned short* __restrict__ qkv,
    const float* __restrict__ rpb,
    unsigned short* __restrict__ out)
{
  __shared__ float kv[2][49][32];
  int blk = blockIdx.x;
  int win = blk / 6, h = blk - win * 6;
  int lane = threadIdx.x;
  const unsigned short* kb = qkv + ((size_t)(win*3 + 1)*6 + h) * 1568;
  const unsigned short* vb = qkv + ((size_t)(win*3 + 2)*6 + h) * 1568;
  for (int idx = lane; idx < 196; idx += 64) {
    V8 kk, vv;
    kk.u = *reinterpret_cast<const uint4*>(kb + idx * 8);
    vv.u = *reinterpret_cast<const uint4*>(vb + idx * 8);
    int n = idx >> 2, sg = (idx & 3) * 8;
    #pragma unroll
    for (int j = 0; j < 8; ++j) { kv[0][n][sg+j] = bf2f(kk.s[j]); kv[1][n][sg+j] = bf2f(vv.s[j]); }
  }
  __syncthreads();
  if (lane < 49) {
    float q[32];
    const unsigned short* qr = qkv + ((size_t)(win*3 + 0)*6 + h) * 1568 + lane * 32;
    #pragma unroll
    for (int sg = 0; sg < 4; ++sg) {
      V8 qq; qq.u = *reinterpret_cast<const uint4*>(qr + sg*8);
      #pragma unroll
      for (int j = 0; j < 8; ++j) q[sg*8+j] = bf2f(qq.s[j]) * SCALE_;
    }
    int ti = lane / 7, tj = lane - ti * 7;
    int wi = win & 63, wh = wi >> 3, ww = wi & 7;
    int rid = 0;
    if (SHIFTED) {
      int hh = wh*7 + ti, wg = ww*7 + tj;
      rid = (hh < 49 ? 0 : (hh < 53 ? 1 : 2)) * 3 + (wg < 49 ? 0 : (wg < 53 ? 1 : 2));
    }
    float s[49];
    float mx = -1e30f;
    #pragma unroll
    for (int m = 0; m < 49; ++m) {
      float a = 0.f;
      #pragma unroll
      for (int d4 = 0; d4 < 8; ++d4) {
        float4 kf = *reinterpret_cast<const float4*>(&kv[0][m][d4*4]);
        a += q[d4*4+0]*kf.x + q[d4*4+1]*kf.y + q[d4*4+2]*kf.z + q[d4*4+3]*kf.w;
      }
      int mi = m / 7, mj = m - mi * 7;
      a += rpb[((ti - mi + 6) * 13 + (tj - mj + 6)) * 6 + h];
      if (SHIFTED) {
        int hh = wh*7 + mi, wg = ww*7 + mj;
        int rid2 = (hh < 49 ? 0 : (hh < 53 ? 1 : 2)) * 3 + (wg < 49 ? 0 : (wg < 53 ? 1 : 2));
        if (rid2 != rid) a -= 100.f;
      }
      s[m] = a;
      mx = fmaxf(mx, a);
    }
    float sum = 0.f;
    #pragma unroll
    for (int m = 0; m < 49; ++m) { float e = __expf(s[m] - mx); s[m] = e; sum += e; }
    float rs = 1.f / sum;
    float o[32];
    #pragma unroll
    for (int d = 0; d < 32; ++d) o[d] = 0.f;
    #pragma unroll
    for (int m = 0; m < 49; ++m) {
      float p = s[m] * rs;
      #pragma unroll
      for (int d4 = 0; d4 < 8; ++d4) {
        float4 vf = *reinterpret_cast<const float4*>(&kv[1][m][d4*4]);
        o[d4*4+0] += p*vf.x; o[d4*4+1] += p*vf.y; o[d4*4+2] += p*vf.z; o[d4*4+3] += p*vf.w;
      }
    }
    unsigned short* orow = out + ((size_t)win * 49 + lane) * 192 + h * 32;
    #pragma unroll
    for (int sg = 0; sg < 4; ++sg) {
      V8 pk;
      #pragma unroll
      for (int j = 0; j < 8; ++j) pk.s[j] = f2bf(o[sg*8+j]);
      *reinterpret_cast<uint4*>(orow + sg*8) = pk.u;
    }
  }
}

// ---------------- launch ----------------
extern "C" void kernel_launch(void* const* d_in, const int* in_sizes, int n_in,
                              void* d_out, int out_size, void* d_ws, size_t ws_size,
                              hipStream_t stream) {
  const float* x    = (const float*)d_in[0];
  const float* n1g  = (const float*)d_in[1];
  const float* n1b  = (const float*)d_in[2];
  const float* qkvw = (const float*)d_in[3];
  const float* qkvb = (const float*)d_in[4];
  const float* rpb  = (const float*)d_in[5];
  const float* pw   = (const float*)d_in[6];
  const float* pb   = (const float*)d_in[7];
  const float* n2g  = (const float*)d_in[8];
  const float* n2b  = (const float*)d_in[9];
  const float* f1w  = (const float*)d_in[10];
  const float* f1b  = (const float*)d_in[11];
  const float* f2w  = (const float*)d_in[12];
  const float* f2b  = (const float*)d_in[13];
  float* out = (float*)d_out;

  const size_t XBYTES = (size_t)MROWS * 192 * 4;
  const size_t ABYTES = (size_t)MROWS * 192 * 2;
  const size_t QBYTES = (size_t)MROWS * 576 * 2;
  char* ws = (char*)d_ws;
  float* x1 = (float*)ws;
  unsigned short* Abuf = (unsigned short*)(ws + XBYTES);
  unsigned short* Bbuf = (unsigned short*)(ws + XBYTES + ABYTES);
  unsigned short* WT   = (unsigned short*)(ws + XBYTES + ABYTES + QBYTES);

  // all weight conversions in one 2D launch (y = depth)
  wtall_k<<<dim3((WD + 255)/256, 2), 256, 0, stream>>>(qkvw, pw, f1w, f2w, WT);

  const dim3 G_P(MROWS/128, 3);

  for (int i = 0; i < 2; ++i) {
    int shift = i ? 3 : 0;
    const float* xin = i ? (const float*)x1 : x;
    float* xfin = i ? out : x1;
    const unsigned short* wt = WT + (size_t)i * WD;
    // 1. fused LN1 + window gather + QKV gemm -> Bbuf [win][qkv][head][tok][32]
    qkvf_k<<<MROWS/128, 256, 0, stream>>>(xin, n1g + i*192, n1b + i*192, wt,
                                          qkvb + i*576, Bbuf, shift);
    // 2. attention -> Abuf (row-major [win*49+tok][192])
    if (shift) attn_k<true ><<<4096*6, 64, 0, stream>>>(Bbuf, rpb + i*169*6, Abuf);
    else       attn_k<false><<<4096*6, 64, 0, stream>>>(Bbuf, rpb + i*169*6, Abuf);
    // 3. proj gemm + window-reverse scatter residual -> x1
    proj_k<<<G_P, 256, 0, stream>>>(Abuf, wt + WQ, pb + i*192, xin, x1, shift);
    // 4. fused LN2 + FC1 + GELU + FC2 + residual
    mlp_k<<<MROWS/64, 512, 0, stream>>>(x1, n2g + i*192, n2b + i*192,
                                        wt + WQ + WP, f1b + i*768,
                                        wt + WQ + WP + W1, f2b + i*192, xfin);
  }
}

// Round 13
// 1990.976 us; speedup vs baseline: 1.0077x; 1.0024x over previous
//
#include <hip/hip_runtime.h>
#include <stdint.h>

#define MROWS  200704
#define SCALE_ 0.17677669529663687f  // 32^-0.5
#define WQ 110592
#define WP 36864
#define W1 147456
#define W2 147456
#define WD (WQ + WP + W1 + W2)

typedef __attribute__((ext_vector_type(8))) short bf16x8;
typedef __attribute__((ext_vector_type(4))) float f32x4;
union V8 { uint4 u; unsigned short s[8]; };

__device__ __forceinline__ float bf2f(unsigned short u) {
  union { unsigned int i; float f; } c; c.i = ((unsigned int)u) << 16; return c.f;
}
__device__ __forceinline__ unsigned short f2bf(float f) {
  union { float f; unsigned int i; } c; c.f = f;
  unsigned int lsb = (c.i >> 16) & 1;
  return (unsigned short)((c.i + 0x7fffu + lsb) >> 16);
}
// tanh-form GELU, exp-based; validated round 5/7
__device__ __forceinline__ float gelu_f(float x) {
  float x2 = x * x;
  float arg = x * fmaf(0.07135481f, x2, 1.59576912f);
  float e = __expf(arg);
  float r = __builtin_amdgcn_rcpf(1.0f + e);
  return fmaf(-x, r, x);
}

// ---------------- combined weight convert+transpose (all 4 weights, both depths) ----------------
__global__ __launch_bounds__(256) void wtall_k(const float* __restrict__ qkvw,
    const float* __restrict__ pw, const float* __restrict__ f1w,
    const float* __restrict__ f2w, unsigned short* __restrict__ WT)
{
  int d = blockIdx.y;
  int j = blockIdx.x * 256 + threadIdx.x;
  if (j >= WD) return;
  unsigned short* wt = WT + (size_t)d * WD;
  if (j < WQ) {
    const float* W = qkvw + (size_t)d * WQ;
    int k = j / 576, n = j - k * 576;
    wt[n * 192 + k] = f2bf(W[j]);
  } else if (j < WQ + WP) {
    int j2 = j - WQ;
    const float* W = pw + (size_t)d * WP;
    int k = j2 / 192, n = j2 - k * 192;
    (wt + WQ)[n * 192 + k] = f2bf(W[j2]);
  } else if (j < WQ + WP + W1) {
    int j2 = j - WQ - WP;
    const float* W = f1w + (size_t)d * W1;
    int k = j2 / 768, n = j2 - k * 768;
    (wt + WQ + WP)[n * 192 + k] = f2bf(W[j2]);
  } else {
    int j2 = j - WQ - WP - W1;
    const float* W = f2w + (size_t)d * W2;
    int k = j2 / 192, n = j2 - k * 192;
    (wt + WQ + WP + W1)[(size_t)n * 768 + k] = f2bf(W[j2]);
  }
}

// ---------------- FUSED LN1 (windowed gather) + QKV GEMM ----------------
// Output layout: Bbuf[win][qkv][head][tok][32]; epilogue addressing hoisted:
// off = winbase(mi,i) + panelbase(p,ni) + fr
__global__ __launch_bounds__(256, 3) void qkvf_k(const float* __restrict__ X,
    const float* __restrict__ g, const float* __restrict__ b,
    const unsigned short* __restrict__ Wt,   // [576][192] bf16
    const float* __restrict__ bias,
    unsigned short* __restrict__ C, int shift)
{
  __shared__ unsigned short As[128][200];
  const int tid = threadIdx.x, lane = tid & 63, wv = tid >> 6;
  const int row0 = blockIdx.x * 128;
  #pragma unroll 2
  for (int r = 0; r < 32; ++r) {
    int row = wv * 32 + r, wr = row0 + row;
    int win = wr / 49, n = wr - win * 49;
    int bi = win >> 6, w64 = win & 63, wh = w64 >> 3, ww = w64 & 7;
    int ti = n / 7, tj = n - ti * 7;
    int gh = wh*7 + ti + shift; if (gh >= 56) gh -= 56;
    int gw = ww*7 + tj + shift; if (gw >= 56) gw -= 56;
    const float* xr = X + ((size_t)bi*3136 + gh*56 + gw) * 192;
    float v0 = xr[lane], v1 = xr[lane + 64], v2 = xr[lane + 128];
    float s  = v0 + v1 + v2;
    float s2 = v0*v0 + v1*v1 + v2*v2;
    #pragma unroll
    for (int m = 32; m >= 1; m >>= 1) { s += __shfl_xor(s, m); s2 += __shfl_xor(s2, m); }
    float mean = s * (1.0f/192.0f);
    float var  = s2 * (1.0f/192.0f) - mean*mean;
    float inv  = rsqrtf(var + 1e-5f);
    As[row][lane]     = f2bf((v0-mean)*inv*g[lane]      + b[lane]);
    As[row][lane+64]  = f2bf((v1-mean)*inv*g[lane+64]   + b[lane+64]);
    As[row][lane+128] = f2bf((v2-mean)*inv*g[lane+128]  + b[lane+128]);
  }
  __syncthreads();   // the ONLY barrier
  const int wm = wv >> 1, wn = wv & 1;
  const int fr = lane & 15, kq = (lane >> 4) * 8;
  const int lr4 = (lane >> 4) * 4;
  // hoisted per-(mi,i) output bases: win*3*6*1568 + tok*32
  int wbase[16];
  #pragma unroll
  for (int mi = 0; mi < 4; ++mi)
  #pragma unroll
  for (int i = 0; i < 4; ++i) {
    int gr = row0 + wm*64 + mi*16 + lr4 + i;
    int win = gr / 49, tok = gr - win * 49;
    wbase[mi*4 + i] = win * 28224 + tok * 32;   // 3*6*1568 = 28224
  }
  #pragma unroll 1
  for (int p = 0; p < 9; ++p) {
    bf16x8 bfr[6][2];
    #pragma unroll
    for (int ks = 0; ks < 6; ++ks)
      #pragma unroll
      for (int ni = 0; ni < 2; ++ni)
        bfr[ks][ni] = *reinterpret_cast<const bf16x8*>(
            &Wt[(size_t)(p*64 + wn*32 + ni*16 + fr) * 192 + ks*32 + kq]);
    f32x4 acc[4][2] = {};
    #pragma unroll
    for (int ks = 0; ks < 6; ++ks)
      #pragma unroll
      for (int mi = 0; mi < 4; ++mi) {
        bf16x8 afr = *reinterpret_cast<const bf16x8*>(&As[wm*64 + mi*16 + fr][ks*32 + kq]);
        #pragma unroll
        for (int ni = 0; ni < 2; ++ni)
          acc[mi][ni] = __builtin_amdgcn_mfma_f32_16x16x32_bf16(afr, bfr[ks][ni], acc[mi][ni], 0, 0, 0);
      }
    #pragma unroll
    for (int ni = 0; ni < 2; ++ni) {
      int base_gc = p*64 + wn*32 + ni*16;          // compile-time-ish per (p,ni)
      int qkvi = base_gc / 192;
      int rem  = base_gc - qkvi * 192;
      int head = rem >> 5, dd0 = rem & 31;
      int pbase = (qkvi*6 + head) * 1568 + dd0 + fr;
      float bv = bias[base_gc + fr];
      #pragma unroll
      for (int mi = 0; mi < 4; ++mi)
      #pragma unroll
      for (int i = 0; i < 4; ++i)
        C[(size_t)(wbase[mi*4 + i] + pbase)] = f2bf(acc[mi][ni][i] + bv);
    }
  }
}

// ---------------- proj GEMM + window-reverse scatter residual (r7 structure) ----------------
__global__ __launch_bounds__(256, 4) void proj_k(
    const unsigned short* __restrict__ A,
    const unsigned short* __restrict__ Wt,   // [192][192] bf16
    const float* __restrict__ bias,
    const float* __restrict__ Xres,
    float* __restrict__ Xdst,
    int shift)
{
  __shared__ unsigned short As[128][40];
  const int tid = threadIdx.x;
  const int lane = tid & 63, wv = tid >> 6;
  const int wm = wv >> 1, wn = wv & 1;
  const int row0 = blockIdx.x * 128;
  const int n0   = blockIdx.y * 64;
  const int fr = lane & 15, kq = (lane >> 4) * 8;
  bf16x8 bfr[6][2];
  #pragma unroll
  for (int ks = 0; ks < 6; ++ks)
    #pragma unroll
    for (int ni = 0; ni < 2; ++ni)
      bfr[ks][ni] = *reinterpret_cast<const bf16x8*>(
          &Wt[(size_t)(n0 + wn*32 + ni*16 + fr) * 192 + ks*32 + kq]);
  const int sr  = tid >> 1, ssg = (tid & 1) * 16;
  const unsigned short* arow = A + (size_t)(row0 + sr) * 192 + ssg;
  uint4 a0 = *reinterpret_cast<const uint4*>(arow);
  uint4 a1 = *reinterpret_cast<const uint4*>(arow + 8);
  f32x4 acc[4][2] = {};
  #pragma unroll
  for (int ks = 0; ks < 6; ++ks) {
    __syncthreads();
    *reinterpret_cast<uint4*>(&As[sr][ssg])     = a0;
    *reinterpret_cast<uint4*>(&As[sr][ssg + 8]) = a1;
    if (ks < 5) {
      a0 = *reinterpret_cast<const uint4*>(arow + (ks+1)*32);
      a1 = *reinterpret_cast<const uint4*>(arow + (ks+1)*32 + 8);
    }
    __syncthreads();
    #pragma unroll
    for (int mi = 0; mi < 4; ++mi) {
      bf16x8 afr = *reinterpret_cast<const bf16x8*>(&As[wm*64 + mi*16 + fr][kq]);
      #pragma unroll
      for (int ni = 0; ni < 2; ++ni)
        acc[mi][ni] = __builtin_amdgcn_mfma_f32_16x16x32_bf16(afr, bfr[ks][ni], acc[mi][ni], 0, 0, 0);
    }
  }
  const int lcol = lane & 15, lr4 = (lane >> 4) * 4;
  #pragma unroll
  for (int mi = 0; mi < 4; ++mi)
  #pragma unroll
  for (int ni = 0; ni < 2; ++ni)
  #pragma unroll
  for (int i = 0; i < 4; ++i) {
    int gr = row0 + wm*64 + mi*16 + lr4 + i;
    int gc = n0 + wn*32 + ni*16 + lcol;
    float v = acc[mi][ni][i] + bias[gc];
    int win = gr / 49, n = gr % 49;
    int bi = win >> 6, w64 = win & 63;
    int wh = w64 >> 3, ww = w64 & 7;
    int ti = n / 7, tj = n % 7;
    int gh = wh*7 + ti + shift; if (gh >= 56) gh -= 56;
    int gw = ww*7 + tj + shift; if (gw >= 56) gw -= 56;
    size_t idx = ((size_t)bi * 3136 + gh * 56 + gw) * 192 + gc;
    Xdst[idx] = Xres[idx] + v;
  }
}

// ---------------- Fused LN2 + FC1 + GELU + FC2 + residual (r7 verbatim) ----------------
__global__ __launch_bounds__(512, 4) void mlp_k(
    const float* __restrict__ X,
    const float* __restrict__ g, const float* __restrict__ b,
    const unsigned short* __restrict__ W1t, // [768][192] bf16
    const float* __restrict__ b1,
    const unsigned short* __restrict__ W2t, // [192][768] bf16
    const float* __restrict__ b2,
    float* __restrict__ Y)
{
  __shared__ unsigned short As[64][200];
  __shared__ unsigned short Hs[64][396];
  const int row0 = blockIdx.x * 64;
  const int tid = threadIdx.x, lane = tid & 63, wv = tid >> 6;
  #pragma unroll
  for (int r = 0; r < 8; ++r) {
    int row = wv * 8 + r;
    const float* xr = X + (size_t)(row0 + row) * 192;
    float v0 = xr[lane], v1 = xr[lane + 64], v2 = xr[lane + 128];
    float s  = v0 + v1 + v2;
    float s2 = v0*v0 + v1*v1 + v2*v2;
    #pragma unroll
    for (int m = 32; m >= 1; m >>= 1) { s += __shfl_xor(s, m); s2 += __shfl_xor(s2, m); }
    float mean = s * (1.0f/192.0f);
    float var  = s2 * (1.0f/192.0f) - mean*mean;
    float inv  = rsqrtf(var + 1e-5f);
    As[row][lane]       = f2bf((v0-mean)*inv*g[lane]      + b[lane]);
    As[row][lane+64]    = f2bf((v1-mean)*inv*g[lane+64]   + b[lane+64]);
    As[row][lane+128]   = f2bf((v2-mean)*inv*g[lane+128]  + b[lane+128]);
  }
  __syncthreads();
  const int fr = lane & 15, kq = (lane >> 4) * 8;
  const int lcol = lane & 15, lr4 = (lane >> 4) * 4;
  const int wm2 = wv >> 2, wn2 = wv & 3;    // FC2 wave grid: 2 x 4
  f32x4 acc2[2][3] = {};
  for (int hh = 0; hh < 2; ++hh) {
    f32x4 acc1[4][3] = {};
    const int c0 = hh * 384 + wv * 48;
    #pragma unroll
    for (int k0 = 0; k0 < 192; k0 += 32) {
      bf16x8 bfr[3];
      #pragma unroll
      for (int ni = 0; ni < 3; ++ni)
        bfr[ni] = *reinterpret_cast<const bf16x8*>(&W1t[(size_t)(c0 + ni*16 + fr) * 192 + k0 + kq]);
      #pragma unroll
      for (int mi = 0; mi < 4; ++mi) {
        bf16x8 afr = *reinterpret_cast<const bf16x8*>(&As[mi*16 + fr][k0 + kq]);
        #pragma unroll
        for (int ni = 0; ni < 3; ++ni)
          acc1[mi][ni] = __builtin_amdgcn_mfma_f32_16x16x32_bf16(afr, bfr[ni], acc1[mi][ni], 0, 0, 0);
      }
    }
    __syncthreads();   // previous half's FC2 finished reading Hs
    #pragma unroll
    for (int mi = 0; mi < 4; ++mi)
    #pragma unroll
    for (int ni = 0; ni < 3; ++ni)
    #pragma unroll
    for (int i = 0; i < 4; ++i) {
      int rr = mi*16 + lr4 + i;
      int cc = wv*48 + ni*16 + lcol;
      float v = acc1[mi][ni][i] + b1[hh*384 + cc];
      Hs[rr][cc] = f2bf(gelu_f(v));
    }
    __syncthreads();   // Hs ready
    #pragma unroll
    for (int k0 = 0; k0 < 384; k0 += 32) {
      bf16x8 bfr[3];
      #pragma unroll
      for (int ni = 0; ni < 3; ++ni)
        bfr[ni] = *reinterpret_cast<const bf16x8*>(
            &W2t[(size_t)(wn2*48 + ni*16 + fr) * 768 + hh*384 + k0 + kq]);
      #pragma unroll
      for (int mi = 0; mi < 2; ++mi) {
        bf16x8 afr = *reinterpret_cast<const bf16x8*>(&Hs[wm2*32 + mi*16 + fr][k0 + kq]);
        #pragma unroll
        for (int ni = 0; ni < 3; ++ni)
          acc2[mi][ni] = __builtin_amdgcn_mfma_f32_16x16x32_bf16(afr, bfr[ni], acc2[mi][ni], 0, 0, 0);
      }
    }
  }
  #pragma unroll
  for (int mi = 0; mi < 2; ++mi)
  #pragma unroll
  for (int ni = 0; ni < 3; ++ni)
  #pragma unroll
  for (int i = 0; i < 4; ++i) {
    int grow = row0 + wm2*32 + mi*16 + lr4 + i;
    int gc = wn2*48 + ni*16 + lcol;
    float v = acc2[mi][ni][i] + b2[gc];
    size_t idx = (size_t)grow * 192 + gc;
    Y[idx] = X[idx] + v;
  }
}

// ---------------- Windowed attention: one wave per (window, head) ----------------
// qkv layout: [win][qkv][head][tok][32] -> K/V slices fully contiguous (3136 B)
template<bool SHIFTED>
__global__ __launch_bounds__(64) void attn_k(
    const unsigned short* __restrict__ qkv,
    const float* __restrict__ rpb,
    unsigned short* __restrict__ out)
{
  __shared__ float kv[2][49][32];
  int blk = blockIdx.x;
  int win = blk / 6, h = blk - win * 6;
  int lane = threadIdx.x;
  const unsigned short* kb = qkv + ((size_t)(win*3 + 1)*6 + h) * 1568;
  const unsigned short* vb = qkv + ((size_t)(win*3 + 2)*6 + h) * 1568;
  for (int idx = lane; idx < 196; idx += 64) {
    V8 kk, vv;
    kk.u = *reinterpret_cast<const uint4*>(kb + idx * 8);
    vv.u = *reinterpret_cast<const uint4*>(vb + idx * 8);
    int n = idx >> 2, sg = (idx & 3) * 8;
    #pragma unroll
    for (int j = 0; j < 8; ++j) { kv[0][n][sg+j] = bf2f(kk.s[j]); kv[1][n][sg+j] = bf2f(vv.s[j]); }
  }
  __syncthreads();
  if (lane < 49) {
    float q[32];
    const unsigned short* qr = qkv + ((size_t)(win*3 + 0)*6 + h) * 1568 + lane * 32;
    #pragma unroll
    for (int sg = 0; sg < 4; ++sg) {
      V8 qq; qq.u = *reinterpret_cast<const uint4*>(qr + sg*8);
      #pragma unroll
      for (int j = 0; j < 8; ++j) q[sg*8+j] = bf2f(qq.s[j]) * SCALE_;
    }
    int ti = lane / 7, tj = lane - ti * 7;
    int wi = win & 63, wh = wi >> 3, ww = wi & 7;
    int rid = 0;
    if (SHIFTED) {
      int hh = wh*7 + ti, wg = ww*7 + tj;
      rid = (hh < 49 ? 0 : (hh < 53 ? 1 : 2)) * 3 + (wg < 49 ? 0 : (wg < 53 ? 1 : 2));
    }
    float s[49];
    float mx = -1e30f;
    #pragma unroll
    for (int m = 0; m < 49; ++m) {
      float a = 0.f;
      #pragma unroll
      for (int d4 = 0; d4 < 8; ++d4) {
        float4 kf = *reinterpret_cast<const float4*>(&kv[0][m][d4*4]);
        a += q[d4*4+0]*kf.x + q[d4*4+1]*kf.y + q[d4*4+2]*kf.z + q[d4*4+3]*kf.w;
      }
      int mi = m / 7, mj = m - mi * 7;
      a += rpb[((ti - mi + 6) * 13 + (tj - mj + 6)) * 6 + h];
      if (SHIFTED) {
        int hh = wh*7 + mi, wg = ww*7 + mj;
        int rid2 = (hh < 49 ? 0 : (hh < 53 ? 1 : 2)) * 3 + (wg < 49 ? 0 : (wg < 53 ? 1 : 2));
        if (rid2 != rid) a -= 100.f;
      }
      s[m] = a;
      mx = fmaxf(mx, a);
    }
    float sum = 0.f;
    #pragma unroll
    for (int m = 0; m < 49; ++m) { float e = __expf(s[m] - mx); s[m] = e; sum += e; }
    float rs = 1.f / sum;
    float o[32];
    #pragma unroll
    for (int d = 0; d < 32; ++d) o[d] = 0.f;
    #pragma unroll
    for (int m = 0; m < 49; ++m) {
      float p = s[m] * rs;
      #pragma unroll
      for (int d4 = 0; d4 < 8; ++d4) {
        float4 vf = *reinterpret_cast<const float4*>(&kv[1][m][d4*4]);
        o[d4*4+0] += p*vf.x; o[d4*4+1] += p*vf.y; o[d4*4+2] += p*vf.z; o[d4*4+3] += p*vf.w;
      }
    }
    unsigned short* orow = out + ((size_t)win * 49 + lane) * 192 + h * 32;
    #pragma unroll
    for (int sg = 0; sg < 4; ++sg) {
      V8 pk;
      #pragma unroll
      for (int j = 0; j < 8; ++j) pk.s[j] = f2bf(o[sg*8+j]);
      *reinterpret_cast<uint4*>(orow + sg*8) = pk.u;
    }
  }
}

// ---------------- launch ----------------
extern "C" void kernel_launch(void* const* d_in, const int* in_sizes, int n_in,
                              void* d_out, int out_size, void* d_ws, size_t ws_size,
                              hipStream_t stream) {
  const float* x    = (const float*)d_in[0];
  const float* n1g  = (const float*)d_in[1];
  const float* n1b  = (const float*)d_in[2];
  const float* qkvw = (const float*)d_in[3];
  const float* qkvb = (const float*)d_in[4];
  const float* rpb  = (const float*)d_in[5];
  const float* pw   = (const float*)d_in[6];
  const float* pb   = (const float*)d_in[7];
  const float* n2g  = (const float*)d_in[8];
  const float* n2b  = (const float*)d_in[9];
  const float* f1w  = (const float*)d_in[10];
  const float* f1b  = (const float*)d_in[11];
  const float* f2w  = (const float*)d_in[12];
  const float* f2b  = (const float*)d_in[13];
  float* out = (float*)d_out;

  const size_t XBYTES = (size_t)MROWS * 192 * 4;
  const size_t ABYTES = (size_t)MROWS * 192 * 2;
  const size_t QBYTES = (size_t)MROWS * 576 * 2;
  char* ws = (char*)d_ws;
  float* x1 = (float*)ws;
  unsigned short* Abuf = (unsigned short*)(ws + XBYTES);
  unsigned short* Bbuf = (unsigned short*)(ws + XBYTES + ABYTES);
  unsigned short* WT   = (unsigned short*)(ws + XBYTES + ABYTES + QBYTES);

  // all weight conversions in one 2D launch (y = depth)
  wtall_k<<<dim3((WD + 255)/256, 2), 256, 0, stream>>>(qkvw, pw, f1w, f2w, WT);

  const dim3 G_P(MROWS/128, 3);

  for (int i = 0; i < 2; ++i) {
    int shift = i ? 3 : 0;
    const float* xin = i ? (const float*)x1 : x;
    float* xfin = i ? out : x1;
    const unsigned short* wt = WT + (size_t)i * WD;
    // 1. fused LN1 + window gather + QKV gemm -> Bbuf [win][qkv][head][tok][32]
    qkvf_k<<<MROWS/128, 256, 0, stream>>>(xin, n1g + i*192, n1b + i*192, wt,
                                          qkvb + i*576, Bbuf, shift);
    // 2. attention -> Abuf (row-major [win*49+tok][192])
    if (shift) attn_k<true ><<<4096*6, 64, 0, stream>>>(Bbuf, rpb + i*169*6, Abuf);
    else       attn_k<false><<<4096*6, 64, 0, stream>>>(Bbuf, rpb + i*169*6, Abuf);
    // 3. proj gemm + window-reverse scatter residual -> x1
    proj_k<<<G_P, 256, 0, stream>>>(Abuf, wt + WQ, pb + i*192, xin, x1, shift);
    // 4. fused LN2 + FC1 + GELU + FC2 + residual
    mlp_k<<<MROWS/64, 512, 0, stream>>>(x1, n2g + i*192, n2b + i*192,
                                        wt + WQ + WP, f1b + i*768,
                                        wt + WQ + WP + W1, f2b + i*192, xfin);
  }
}

// Round 14
// 1944.995 us; speedup vs baseline: 1.0315x; 1.0236x over previous
//
#include <hip/hip_runtime.h>
#include <stdint.h>

#define MROWS  200704
#define SCALE_ 0.17677669529663687f  // 32^-0.5
#define WQ 110592
#define WP 36864
#define W1 147456
#define W2 147456
#define WD (WQ + WP + W1 + W2)

typedef __attribute__((ext_vector_type(8))) short bf16x8;
typedef __attribute__((ext_vector_type(4))) float f32x4;
union V8 { uint4 u; unsigned short s[8]; };

__device__ __forceinline__ float bf2f(unsigned short u) {
  union { unsigned int i; float f; } c; c.i = ((unsigned int)u) << 16; return c.f;
}
__device__ __forceinline__ unsigned short f2bf(float f) {
  union { float f; unsigned int i; } c; c.f = f;
  unsigned int lsb = (c.i >> 16) & 1;
  return (unsigned short)((c.i + 0x7fffu + lsb) >> 16);
}
// tanh-form GELU, exp-based; validated round 5/7
__device__ __forceinline__ float gelu_f(float x) {
  float x2 = x * x;
  float arg = x * fmaf(0.07135481f, x2, 1.59576912f);
  float e = __expf(arg);
  float r = __builtin_amdgcn_rcpf(1.0f + e);
  return fmaf(-x, r, x);
}

// ---------------- combined weight convert+transpose (all 4 weights, both depths) ----------------
__global__ __launch_bounds__(256) void wtall_k(const float* __restrict__ qkvw,
    const float* __restrict__ pw, const float* __restrict__ f1w,
    const float* __restrict__ f2w, unsigned short* __restrict__ WT)
{
  int d = blockIdx.y;
  int j = blockIdx.x * 256 + threadIdx.x;
  if (j >= WD) return;
  unsigned short* wt = WT + (size_t)d * WD;
  if (j < WQ) {
    const float* W = qkvw + (size_t)d * WQ;
    int k = j / 576, n = j - k * 576;
    wt[n * 192 + k] = f2bf(W[j]);
  } else if (j < WQ + WP) {
    int j2 = j - WQ;
    const float* W = pw + (size_t)d * WP;
    int k = j2 / 192, n = j2 - k * 192;
    (wt + WQ)[n * 192 + k] = f2bf(W[j2]);
  } else if (j < WQ + WP + W1) {
    int j2 = j - WQ - WP;
    const float* W = f1w + (size_t)d * W1;
    int k = j2 / 768, n = j2 - k * 768;
    (wt + WQ + WP)[n * 192 + k] = f2bf(W[j2]);
  } else {
    int j2 = j - WQ - WP - W1;
    const float* W = f2w + (size_t)d * W2;
    int k = j2 / 192, n = j2 - k * 192;
    (wt + WQ + WP + W1)[(size_t)n * 768 + k] = f2bf(W[j2]);
  }
}

// ---------------- LayerNorm + shifted window partition (r7 verbatim) ----------------
__global__ __launch_bounds__(256) void ln_k(const float* __restrict__ X,
    const float* __restrict__ g, const float* __restrict__ b,
    unsigned short* __restrict__ out, int shift)
{
  int wr = blockIdx.x * 4 + (threadIdx.x >> 6);
  int lane = threadIdx.x & 63;
  int win = wr / 49, n = wr % 49;
  int bi = win >> 6, w64 = win & 63;
  int wh = w64 >> 3, ww = w64 & 7;
  int ti = n / 7, tj = n % 7;
  int gh = wh * 7 + ti + shift; if (gh >= 56) gh -= 56;
  int gw = ww * 7 + tj + shift; if (gw >= 56) gw -= 56;
  size_t srow = (size_t)bi * 3136 + gh * 56 + gw;
  const float* xr = X + srow * 192;
  float v0 = xr[lane], v1 = xr[lane + 64], v2 = xr[lane + 128];
  float s  = v0 + v1 + v2;
  float s2 = v0*v0 + v1*v1 + v2*v2;
  #pragma unroll
  for (int m = 32; m >= 1; m >>= 1) { s += __shfl_xor(s, m); s2 += __shfl_xor(s2, m); }
  float mean = s * (1.0f/192.0f);
  float var  = s2 * (1.0f/192.0f) - mean*mean;
  float inv  = rsqrtf(var + 1e-5f);
  unsigned short* orow = out + (size_t)wr * 192;
  orow[lane]       = f2bf((v0-mean)*inv*g[lane]      + b[lane]);
  orow[lane+64]    = f2bf((v1-mean)*inv*g[lane+64]   + b[lane+64]);
  orow[lane+128]   = f2bf((v2-mean)*inv*g[lane+128]  + b[lane+128]);
}

// ---------------- MFMA GEMM (K=192), r7 verbatim ----------------
// EPI: 0 = write bf16 (qkv); 1 = proj: window-reverse scatter + residual (N==192)
template<int EPI>
__global__ __launch_bounds__(256, 4) void gemm2_k(
    const unsigned short* __restrict__ A,
    const unsigned short* __restrict__ Wt,   // [N][192] bf16
    const float* __restrict__ bias,
    unsigned short* __restrict__ Cbf,
    const float* __restrict__ Xres,
    float* __restrict__ Xdst,
    int N, int shift)
{
  __shared__ unsigned short As[128][40];
  const int tid = threadIdx.x;
  const int lane = tid & 63, wv = tid >> 6;
  const int wm = wv >> 1, wn = wv & 1;
  const int row0 = blockIdx.x * 128;
  const int n0   = blockIdx.y * 64;
  const int fr = lane & 15, kq = (lane >> 4) * 8;
  bf16x8 bfr[6][2];
  #pragma unroll
  for (int ks = 0; ks < 6; ++ks)
    #pragma unroll
    for (int ni = 0; ni < 2; ++ni)
      bfr[ks][ni] = *reinterpret_cast<const bf16x8*>(
          &Wt[(size_t)(n0 + wn*32 + ni*16 + fr) * 192 + ks*32 + kq]);
  const int sr  = tid >> 1, ssg = (tid & 1) * 16;
  const unsigned short* arow = A + (size_t)(row0 + sr) * 192 + ssg;
  uint4 a0 = *reinterpret_cast<const uint4*>(arow);
  uint4 a1 = *reinterpret_cast<const uint4*>(arow + 8);
  f32x4 acc[4][2] = {};
  #pragma unroll
  for (int ks = 0; ks < 6; ++ks) {
    __syncthreads();
    *reinterpret_cast<uint4*>(&As[sr][ssg])     = a0;
    *reinterpret_cast<uint4*>(&As[sr][ssg + 8]) = a1;
    if (ks < 5) {
      a0 = *reinterpret_cast<const uint4*>(arow + (ks+1)*32);
      a1 = *reinterpret_cast<const uint4*>(arow + (ks+1)*32 + 8);
    }
    __syncthreads();
    #pragma unroll
    for (int mi = 0; mi < 4; ++mi) {
      bf16x8 afr = *reinterpret_cast<const bf16x8*>(&As[wm*64 + mi*16 + fr][kq]);
      #pragma unroll
      for (int ni = 0; ni < 2; ++ni)
        acc[mi][ni] = __builtin_amdgcn_mfma_f32_16x16x32_bf16(afr, bfr[ks][ni], acc[mi][ni], 0, 0, 0);
    }
  }
  const int lcol = lane & 15, lr4 = (lane >> 4) * 4;
  #pragma unroll
  for (int mi = 0; mi < 4; ++mi)
  #pragma unroll
  for (int ni = 0; ni < 2; ++ni)
  #pragma unroll
  for (int i = 0; i < 4; ++i) {
    int gr = row0 + wm*64 + mi*16 + lr4 + i;
    int gc = n0 + wn*32 + ni*16 + lcol;
    float v = acc[mi][ni][i] + bias[gc];
    if (EPI == 0) {
      Cbf[(size_t)gr * N + gc] = f2bf(v);
    } else {
      int win = gr / 49, n = gr % 49;
      int bi = win >> 6, w64 = win & 63;
      int wh = w64 >> 3, ww = w64 & 7;
      int ti = n / 7, tj = n % 7;
      int gh = wh*7 + ti + shift; if (gh >= 56) gh -= 56;
      int gw = ww*7 + tj + shift; if (gw >= 56) gw -= 56;
      size_t idx = ((size_t)bi * 3136 + gh * 56 + gw) * 192 + gc;
      Xdst[idx] = Xres[idx] + v;
    }
  }
}

// ---------------- Fused LN2 + FC1 + GELU + FC2 + residual (r7 verbatim) ----------------
__global__ __launch_bounds__(512, 4) void mlp_k(
    const float* __restrict__ X,
    const float* __restrict__ g, const float* __restrict__ b,
    const unsigned short* __restrict__ W1t, // [768][192] bf16
    const float* __restrict__ b1,
    const unsigned short* __restrict__ W2t, // [192][768] bf16
    const float* __restrict__ b2,
    float* __restrict__ Y)
{
  __shared__ unsigned short As[64][200];
  __shared__ unsigned short Hs[64][396];
  const int row0 = blockIdx.x * 64;
  const int tid = threadIdx.x, lane = tid & 63, wv = tid >> 6;
  #pragma unroll
  for (int r = 0; r < 8; ++r) {
    int row = wv * 8 + r;
    const float* xr = X + (size_t)(row0 + row) * 192;
    float v0 = xr[lane], v1 = xr[lane + 64], v2 = xr[lane + 128];
    float s  = v0 + v1 + v2;
    float s2 = v0*v0 + v1*v1 + v2*v2;
    #pragma unroll
    for (int m = 32; m >= 1; m >>= 1) { s += __shfl_xor(s, m); s2 += __shfl_xor(s2, m); }
    float mean = s * (1.0f/192.0f);
    float var  = s2 * (1.0f/192.0f) - mean*mean;
    float inv  = rsqrtf(var + 1e-5f);
    As[row][lane]       = f2bf((v0-mean)*inv*g[lane]      + b[lane]);
    As[row][lane+64]    = f2bf((v1-mean)*inv*g[lane+64]   + b[lane+64]);
    As[row][lane+128]   = f2bf((v2-mean)*inv*g[lane+128]  + b[lane+128]);
  }
  __syncthreads();
  const int fr = lane & 15, kq = (lane >> 4) * 8;
  const int lcol = lane & 15, lr4 = (lane >> 4) * 4;
  const int wm2 = wv >> 2, wn2 = wv & 3;
  f32x4 acc2[2][3] = {};
  for (int hh = 0; hh < 2; ++hh) {
    f32x4 acc1[4][3] = {};
    const int c0 = hh * 384 + wv * 48;
    #pragma unroll
    for (int k0 = 0; k0 < 192; k0 += 32) {
      bf16x8 bfr[3];
      #pragma unroll
      for (int ni = 0; ni < 3; ++ni)
        bfr[ni] = *reinterpret_cast<const bf16x8*>(&W1t[(size_t)(c0 + ni*16 + fr) * 192 + k0 + kq]);
      #pragma unroll
      for (int mi = 0; mi < 4; ++mi) {
        bf16x8 afr = *reinterpret_cast<const bf16x8*>(&As[mi*16 + fr][k0 + kq]);
        #pragma unroll
        for (int ni = 0; ni < 3; ++ni)
          acc1[mi][ni] = __builtin_amdgcn_mfma_f32_16x16x32_bf16(afr, bfr[ni], acc1[mi][ni], 0, 0, 0);
      }
    }
    __syncthreads();
    #pragma unroll
    for (int mi = 0; mi < 4; ++mi)
    #pragma unroll
    for (int ni = 0; ni < 3; ++ni)
    #pragma unroll
    for (int i = 0; i < 4; ++i) {
      int rr = mi*16 + lr4 + i;
      int cc = wv*48 + ni*16 + lcol;
      float v = acc1[mi][ni][i] + b1[hh*384 + cc];
      Hs[rr][cc] = f2bf(gelu_f(v));
    }
    __syncthreads();
    #pragma unroll
    for (int k0 = 0; k0 < 384; k0 += 32) {
      bf16x8 bfr[3];
      #pragma unroll
      for (int ni = 0; ni < 3; ++ni)
        bfr[ni] = *reinterpret_cast<const bf16x8*>(
            &W2t[(size_t)(wn2*48 + ni*16 + fr) * 768 + hh*384 + k0 + kq]);
      #pragma unroll
      for (int mi = 0; mi < 2; ++mi) {
        bf16x8 afr = *reinterpret_cast<const bf16x8*>(&Hs[wm2*32 + mi*16 + fr][k0 + kq]);
        #pragma unroll
        for (int ni = 0; ni < 3; ++ni)
          acc2[mi][ni] = __builtin_amdgcn_mfma_f32_16x16x32_bf16(afr, bfr[ni], acc2[mi][ni], 0, 0, 0);
      }
    }
  }
  #pragma unroll
  for (int mi = 0; mi < 2; ++mi)
  #pragma unroll
  for (int ni = 0; ni < 3; ++ni)
  #pragma unroll
  for (int i = 0; i < 4; ++i) {
    int grow = row0 + wm2*32 + mi*16 + lr4 + i;
    int gc = wn2*48 + ni*16 + lcol;
    float v = acc2[mi][ni][i] + b2[gc];
    size_t idx = (size_t)grow * 192 + gc;
    Y[idx] = X[idx] + v;
  }
}

// ---------------- Windowed attention v2 ----------------
// 4 (win,head) jobs per 256-thread block (1 wave each); K/V staged as raw bf16
// in LDS (padded rows); single fused pass: e=exp(score), sum+=e, o+=e*V[m]
// (scores bounded => no max-subtraction needed; masked entries exp(a-100)->0).
// Dot uses 4 split accumulators to break the serial fma chain.
template<bool SHIFTED>
__global__ __launch_bounds__(256) void attn_k(
    const unsigned short* __restrict__ qkv,
    const float* __restrict__ rpb,
    unsigned short* __restrict__ out)
{
  __shared__ unsigned short kvs[4][2][49][40];   // pad 40: aligned b128, spread banks
  const int tid = threadIdx.x, lane = tid & 63, wv = tid >> 6;
  const int g = blockIdx.x * 4 + wv;
  const int win = g / 6, h = g - win * 6;
  const unsigned short* base = qkv + (size_t)win * 49 * 576;
  for (int idx = lane; idx < 196; idx += 64) {
    int n = idx >> 2, sg = (idx & 3) * 8;
    uint4 kk = *reinterpret_cast<const uint4*>(base + n*576 + 192 + h*32 + sg);
    uint4 vv = *reinterpret_cast<const uint4*>(base + n*576 + 384 + h*32 + sg);
    *reinterpret_cast<uint4*>(&kvs[wv][0][n][sg]) = kk;
    *reinterpret_cast<uint4*>(&kvs[wv][1][n][sg]) = vv;
  }
  __syncthreads();
  if (lane < 49) {
    float q[32];
    const unsigned short* qr = base + (size_t)lane * 576 + h * 32;
    #pragma unroll
    for (int sg = 0; sg < 4; ++sg) {
      V8 qq; qq.u = *reinterpret_cast<const uint4*>(qr + sg*8);
      #pragma unroll
      for (int j = 0; j < 8; ++j) q[sg*8+j] = bf2f(qq.s[j]) * SCALE_;
    }
    int ti = lane / 7, tj = lane - ti * 7;
    int wi = win & 63, wh = wi >> 3, ww = wi & 7;
    int rid = 0;
    if (SHIFTED) {
      int hh = wh*7 + ti, wg = ww*7 + tj;
      rid = (hh < 49 ? 0 : (hh < 53 ? 1 : 2)) * 3 + (wg < 49 ? 0 : (wg < 53 ? 1 : 2));
    }
    float o[32];
    #pragma unroll
    for (int d = 0; d < 32; ++d) o[d] = 0.f;
    float sum = 0.f;
    #pragma unroll 1
    for (int m = 0; m < 49; ++m) {
      float a0 = 0.f, a1 = 0.f, a2 = 0.f, a3 = 0.f;
      #pragma unroll
      for (int d8 = 0; d8 < 4; ++d8) {
        bf16x8 kf = *reinterpret_cast<const bf16x8*>(&kvs[wv][0][m][d8*8]);
        a0 = fmaf(q[d8*8+0], bf2f((unsigned short)kf[0]), a0);
        a1 = fmaf(q[d8*8+1], bf2f((unsigned short)kf[1]), a1);
        a2 = fmaf(q[d8*8+2], bf2f((unsigned short)kf[2]), a2);
        a3 = fmaf(q[d8*8+3], bf2f((unsigned short)kf[3]), a3);
        a0 = fmaf(q[d8*8+4], bf2f((unsigned short)kf[4]), a0);
        a1 = fmaf(q[d8*8+5], bf2f((unsigned short)kf[5]), a1);
        a2 = fmaf(q[d8*8+6], bf2f((unsigned short)kf[6]), a2);
        a3 = fmaf(q[d8*8+7], bf2f((unsigned short)kf[7]), a3);
      }
      int mi = m / 7, mj = m - mi * 7;
      float a = (a0 + a1) + (a2 + a3)
              + rpb[((ti - mi + 6) * 13 + (tj - mj + 6)) * 6 + h];
      if (SHIFTED) {
        int hh = wh*7 + mi, wg = ww*7 + mj;
        int rid2 = (hh < 49 ? 0 : (hh < 53 ? 1 : 2)) * 3 + (wg < 49 ? 0 : (wg < 53 ? 1 : 2));
        if (rid2 != rid) a -= 100.f;
      }
      float e = __expf(a);
      sum += e;
      #pragma unroll
      for (int d8 = 0; d8 < 4; ++d8) {
        bf16x8 vf = *reinterpret_cast<const bf16x8*>(&kvs[wv][1][m][d8*8]);
        #pragma unroll
        for (int j = 0; j < 8; ++j)
          o[d8*8+j] = fmaf(e, bf2f((unsigned short)vf[j]), o[d8*8+j]);
      }
    }
    float rs = 1.f / sum;
    unsigned short* orow = out + ((size_t)win * 49 + lane) * 192 + h * 32;
    #pragma unroll
    for (int sg = 0; sg < 4; ++sg) {
      V8 pk;
      #pragma unroll
      for (int j = 0; j < 8; ++j) pk.s[j] = f2bf(o[sg*8+j] * rs);
      *reinterpret_cast<uint4*>(orow + sg*8) = pk.u;
    }
  }
}

// ---------------- launch ----------------
extern "C" void kernel_launch(void* const* d_in, const int* in_sizes, int n_in,
                              void* d_out, int out_size, void* d_ws, size_t ws_size,
                              hipStream_t stream) {
  const float* x    = (const float*)d_in[0];
  const float* n1g  = (const float*)d_in[1];
  const float* n1b  = (const float*)d_in[2];
  const float* qkvw = (const float*)d_in[3];
  const float* qkvb = (const float*)d_in[4];
  const float* rpb  = (const float*)d_in[5];
  const float* pw   = (const float*)d_in[6];
  const float* pb   = (const float*)d_in[7];
  const float* n2g  = (const float*)d_in[8];
  const float* n2b  = (const float*)d_in[9];
  const float* f1w  = (const float*)d_in[10];
  const float* f1b  = (const float*)d_in[11];
  const float* f2w  = (const float*)d_in[12];
  const float* f2b  = (const float*)d_in[13];
  float* out = (float*)d_out;

  const size_t XBYTES = (size_t)MROWS * 192 * 4;
  const size_t ABYTES = (size_t)MROWS * 192 * 2;
  const size_t QBYTES = (size_t)MROWS * 576 * 2;
  char* ws = (char*)d_ws;
  float* x1 = (float*)ws;
  unsigned short* Abuf = (unsigned short*)(ws + XBYTES);
  unsigned short* Bbuf = (unsigned short*)(ws + XBYTES + ABYTES);
  unsigned short* WT   = (unsigned short*)(ws + XBYTES + ABYTES + QBYTES);

  wtall_k<<<dim3((WD + 255)/256, 2), 256, 0, stream>>>(qkvw, pw, f1w, f2w, WT);

  const int LNBLK = MROWS / 4;
  const dim3 G_QKV(MROWS/128, 9), G_P(MROWS/128, 3);

  for (int i = 0; i < 2; ++i) {
    int shift = i ? 3 : 0;
    const float* xin = i ? (const float*)x1 : x;
    float* xfin = i ? out : x1;
    const unsigned short* wt = WT + (size_t)i * WD;
    // 1. LN1 + shifted window partition -> Abuf
    ln_k<<<LNBLK, 256, 0, stream>>>(xin, n1g + i*192, n1b + i*192, Abuf, shift);
    // 2. QKV gemm -> Bbuf (row-major [row][576])
    gemm2_k<0><<<G_QKV, 256, 0, stream>>>(Abuf, wt, qkvb + i*576, Bbuf, nullptr, nullptr, 576, 0);
    // 3. attention (4 jobs/block) -> Abuf
    if (shift) attn_k<true ><<<4096*6/4, 256, 0, stream>>>(Bbuf, rpb + i*169*6, Abuf);
    else       attn_k<false><<<4096*6/4, 256, 0, stream>>>(Bbuf, rpb + i*169*6, Abuf);
    // 4. proj gemm + window-reverse scatter residual -> x1
    gemm2_k<1><<<G_P, 256, 0, stream>>>(Abuf, wt + WQ, pb + i*192, nullptr, xin, x1, 192, shift);
    // 5. fused LN2 + FC1 + GELU + FC2 + residual
    mlp_k<<<MROWS/64, 512, 0, stream>>>(x1, n2g + i*192, n2b + i*192,
                                        wt + WQ + WP, f1b + i*768,
                                        wt + WQ + WP + W1, f2b + i*192, xfin);
  }
}